// Round 10
// baseline (788.255 us; speedup 1.0000x reference)
//
#include <hip/hip_runtime.h>

#define NN 200000
#define NE 5000000
#define DIN 128
#define HID 16
#define DOUT 2
#define BSH 9            // dst-buckets of 512 nodes
#define BSZ 512
#define NB 391           // ceil(NN/512)
#define NCH 8            // src slices of 25000 nodes (1.6 MB of xs' @ HID=16)
#define SLICE_DIV 25000
#define NK (NB * NCH)    // 3128 sort keys
#define PB 128           // partition grid blocks (16/XCD -> 3.2MB open write lines < L2)
#define PT 512           // partition block threads
#define CAP 4096         // max edges per (bucket,slice) segment; mean 1599

static_assert((NN + BSZ - 1) / BSZ == NB, "bucket count");
static_assert((NN - 1) / SLICE_DIV == NCH - 1, "slice count");

// ---------------- stage 1: counting sort by (dst>>9, src/25000) ----------------

__global__ __launch_bounds__(PT) void hist_pass(const int* __restrict__ src,
                                                const int* __restrict__ dst,
                                                int* __restrict__ blockHist) {
    __shared__ int h[NK];  // 12.5 KB
    for (int k = threadIdx.x; k < NK; k += PT) h[k] = 0;
    __syncthreads();
    for (int i = blockIdx.x * PT + threadIdx.x; i < NE; i += PB * PT) {
        int dv = __builtin_nontemporal_load(dst + i);
        int sv = __builtin_nontemporal_load(src + i);
        atomicAdd(&h[((dv >> BSH) << 3) + sv / SLICE_DIV], 1);
    }
    __syncthreads();
    for (int k = threadIdx.x; k < NK; k += PT)
        blockHist[(size_t)blockIdx.x * NK + k] = h[k];
}

// per-key totals -> chunkStart[k] (unscanned)
__global__ __launch_bounds__(256) void tot_pass(const int* __restrict__ blockHist,
                                                int* __restrict__ chunkStart) {
    int k = blockIdx.x * 256 + threadIdx.x;
    if (k >= NK) return;
    int s = 0;
#pragma unroll 8
    for (int b = 0; b < PB; ++b) s += blockHist[(size_t)b * NK + k];
    chunkStart[k] = s;
}

// exclusive scan of chunkStart[0..NK) in place (single block)
__global__ __launch_bounds__(1024) void scan_keys(int* __restrict__ chunkStart) {
    __shared__ int psum[1024];
    int t = threadIdx.x;
    const int KPT = (NK + 1023) / 1024;  // 4
    int k0 = t * KPT; if (k0 > NK) k0 = NK;
    int k1 = k0 + KPT; if (k1 > NK) k1 = NK;
    int vals[4];
    int s = 0;
    for (int k = k0; k < k1; ++k) { vals[k - k0] = chunkStart[k]; s += vals[k - k0]; }
    psum[t] = s;
    __syncthreads();
    for (int off = 1; off < 1024; off <<= 1) {
        int add = (t >= off) ? psum[t - off] : 0;
        __syncthreads();
        psum[t] += add;
        __syncthreads();
    }
    int run = psum[t] - s;
    for (int k = k0; k < k1; ++k) { chunkStart[k] = run; run += vals[k - k0]; }
    if (t == 0) chunkStart[NK] = NE;
}

// per-(key, block) exclusive offsets into blockHist
__global__ __launch_bounds__(256) void offsets_pass(int* __restrict__ blockHist,
                                                    const int* __restrict__ chunkStart) {
    int k = blockIdx.x * 256 + threadIdx.x;
    if (k >= NK) return;
    int r = chunkStart[k];
#pragma unroll 8
    for (int b = 0; b < PB; ++b) {
        size_t idx = (size_t)b * NK + k;
        int v = blockHist[idx];
        blockHist[idx] = r;
        r += v;
    }
}

__global__ __launch_bounds__(PT) void scatter_pass(const int* __restrict__ src,
                                                   const int* __restrict__ dst,
                                                   const int* __restrict__ blockHist,
                                                   unsigned* __restrict__ pedge) {
    __shared__ int cur[NK];  // 12.5 KB
    for (int k = threadIdx.x; k < NK; k += PT)
        cur[k] = blockHist[(size_t)blockIdx.x * NK + k];
    __syncthreads();
    // MUST traverse edges in the same per-block order as hist_pass
    for (int i = blockIdx.x * PT + threadIdx.x; i < NE; i += PB * PT) {
        int sv = __builtin_nontemporal_load(src + i);
        int dv = __builtin_nontemporal_load(dst + i);
        int key = ((dv >> BSH) << 3) + sv / SLICE_DIV;
        int pos = atomicAdd(&cur[key], 1);  // LDS atomic only
        pedge[pos] = ((unsigned)sv << BSH) | (unsigned)(dv & (BSZ - 1));
    }
}

// ---------------- stage 2: within-segment sort by dst -> CSR (one-time) ----------------

__global__ __launch_bounds__(512) void subsort(const unsigned* __restrict__ pedge,
                                               const int* __restrict__ chunkStart,
                                               int* __restrict__ pedge2,
                                               int* __restrict__ rowStart,
                                               float* __restrict__ dis) {
    __shared__ unsigned ebuf[CAP];  // 16 KB
    __shared__ int hist[BSZ];
    __shared__ int cur[BSZ];
    __shared__ int wsum[8];
    int t = threadIdx.x;
    int b = blockIdx.x;
    int lane = t & 63, w = t >> 6;
    int deg = 1;  // self loop
    for (int s = 0; s < NCH; ++s) {
        int seg = b * NCH + s;
        int e0 = chunkStart[seg], e1 = chunkStart[seg + 1];
        int n = e1 - e0;
        hist[t] = 0;
        __syncthreads();
        for (int i = t; i < n; i += 512) {
            unsigned p = __builtin_nontemporal_load(pedge + e0 + i);
            ebuf[i] = p;
            atomicAdd(&hist[p & (BSZ - 1u)], 1);
        }
        __syncthreads();
        int v = hist[t];
        deg += v;
        int inc = v;  // wave-inclusive scan
        for (int off = 1; off < 64; off <<= 1) {
            int nb = __shfl_up(inc, off, 64);
            if (lane >= off) inc += nb;
        }
        if (lane == 63) wsum[w] = inc;
        __syncthreads();
        if (t == 0) {
            int car = 0;
#pragma unroll
            for (int i = 0; i < 8; ++i) { int u = wsum[i]; wsum[i] = car; car += u; }
        }
        __syncthreads();
        int excl = inc - v + wsum[w];
        rowStart[(size_t)seg * BSZ + t] = e0 + excl;
        cur[t] = excl;
        __syncthreads();
        for (int i = t; i < n; i += 512) {
            unsigned p = ebuf[i];
            int pos = atomicAdd(&cur[p & (BSZ - 1u)], 1);
            pedge2[e0 + pos] = (int)(p >> BSH);
        }
        __syncthreads();
    }
    int node = (b << BSH) + t;
    if (node < NN) dis[node] = rsqrtf((float)deg);
    if (b == 0 && t == 0) rowStart[(size_t)NK * BSZ] = NE;
}

// ---------------- dense GEMMs, epilogue-scaled by dis[row] (xs' = (h@W)*dis) ----------------

#define GXR 64
#define XPAD 132
__global__ __launch_bounds__(256) void gemm_x_w1(const float* __restrict__ x,
                                                 const float* __restrict__ W,
                                                 const float* __restrict__ dis,
                                                 float* __restrict__ out) {
    __shared__ float w[DIN * HID];     // 8 KB
    __shared__ float xt[GXR * XPAD];   // 33 KB
    int t = threadIdx.x;
    for (int i = t; i < DIN * HID; i += 256) w[i] = W[i];
    int rbase = blockIdx.x * GXR;  // NN = 3125 * 64, no tail
    const float4* xg = reinterpret_cast<const float4*>(x + (size_t)rbase * DIN);
    float4* xt4 = reinterpret_cast<float4*>(xt);
    for (int i = t; i < GXR * (DIN / 4); i += 256) {
        int row = i >> 5, kk = i & 31;
        xt4[row * (XPAD / 4) + kk] = xg[i];
    }
    __syncthreads();
    int row = t >> 2;
    int c0 = (t & 3) * 4;
    const float* xr = xt + row * XPAD;
    float ax = 0.f, ay = 0.f, az = 0.f, aw = 0.f;
#pragma unroll 4
    for (int k = 0; k < DIN; ++k) {
        float xv = xr[k];
        float4 wv = *reinterpret_cast<const float4*>(&w[k * HID + c0]);
        ax += xv * wv.x; ay += xv * wv.y; az += xv * wv.z; aw += xv * wv.w;
    }
    int node = rbase + row;
    float dd = dis[node];
    *reinterpret_cast<float4*>(&out[(size_t)node * HID + c0]) =
        make_float4(ax * dd, ay * dd, az * dd, aw * dd);
}

__global__ __launch_bounds__(256) void gemm_h_w16(const float* __restrict__ h,
                                                  const float* __restrict__ W,
                                                  const float* __restrict__ dis,
                                                  float* __restrict__ out) {
    __shared__ float w[HID * HID];
    if (threadIdx.x < HID * HID) w[threadIdx.x] = W[threadIdx.x];
    __syncthreads();
    int row = blockIdx.x * 16 + (threadIdx.x >> 4);
    int c = threadIdx.x & 15;
    if (row >= NN) return;
    const float4* hr = reinterpret_cast<const float4*>(h + (size_t)row * HID);
    float acc = 0.f;
#pragma unroll
    for (int k4 = 0; k4 < HID / 4; ++k4) {
        float4 v = hr[k4];
        acc += v.x * w[(4 * k4 + 0) * HID + c] + v.y * w[(4 * k4 + 1) * HID + c]
             + v.z * w[(4 * k4 + 2) * HID + c] + v.w * w[(4 * k4 + 3) * HID + c];
    }
    out[row * HID + c] = acc * dis[row];
}

__global__ __launch_bounds__(256) void gemm_h_w2(const float* __restrict__ h,
                                                 const float* __restrict__ W,
                                                 const float* __restrict__ dis,
                                                 float* __restrict__ out) {
    int t = blockIdx.x * 256 + threadIdx.x;
    int row = t >> 1;
    int c = t & 1;
    if (row >= NN) return;
    const float* hr = h + (size_t)row * HID;
    float acc = 0.f;
#pragma unroll
    for (int k = 0; k < HID; ++k) acc += hr[k] * W[k * DOUT + c];
    out[row * DOUT + c] = acc * dis[row];
}

// ---------------- aggregation: one fused kernel per conv, register accumulators ----------------
// 391 blocks x 1024 thr, no LDS, <=64 VGPR -> 2 blocks/CU -> ALL blocks co-resident.
// Soft barrier between slices aligns every block on the same 1.6MB src window
// (pure timing fence: bounded spin, no correctness dependency -> no deadlock).

__device__ __forceinline__ void acc_edges(const int* __restrict__ pedge2,
                                          const float4* __restrict__ xs4,
                                          int e0, int e1, int c4, float4& a) {
    int e = e0;
    for (; e + 1 < e1; e += 2) {
        int s0 = __builtin_nontemporal_load(pedge2 + e);
        int s1 = __builtin_nontemporal_load(pedge2 + e + 1);
        float4 u = xs4[(s0 << 2) + c4];
        float4 w = xs4[(s1 << 2) + c4];
        a.x += u.x + w.x; a.y += u.y + w.y; a.z += u.z + w.z; a.w += u.w + w.w;
    }
    if (e < e1) {
        float4 u = xs4[(__builtin_nontemporal_load(pedge2 + e) << 2) + c4];
        a.x += u.x; a.y += u.y; a.z += u.z; a.w += u.w;
    }
}

__global__ __launch_bounds__(1024, 8) void agg16_all(const int* __restrict__ pedge2,
                                                     const int* __restrict__ rowStart,
                                                     const float* __restrict__ xs,
                                                     const float* __restrict__ dis,
                                                     const float* __restrict__ bias,
                                                     float* __restrict__ buf,
                                                     int relu, int* bar) {
    int t = threadIdx.x;
    int b = blockIdx.x;
    int base = b << BSH;
    int c4 = t & 3;
    int g = t >> 2;  // rows g and g+256 of this bucket
    const float4* xs4 = reinterpret_cast<const float4*>(xs);
    float4* buf4 = reinterpret_cast<float4*>(buf);
    int n0 = base + g, n1 = base + g + 256;
    float4 a0 = make_float4(0.f, 0.f, 0.f, 0.f);
    float4 a1 = make_float4(0.f, 0.f, 0.f, 0.f);
    if (n0 < NN) a0 = xs4[(n0 << 2) + c4];  // self-loop term
    if (n1 < NN) a1 = xs4[(n1 << 2) + c4];
    for (int r = 0; r < NCH; ++r) {
        const int* rs = rowStart + (size_t)(b * NCH + r) * BSZ;
        acc_edges(pedge2, xs4, rs[g], rs[g + 1], c4, a0);
        acc_edges(pedge2, xs4, rs[g + 256], rs[g + 257], c4, a1);
        if (r < NCH - 1) {  // soft slice-alignment barrier
            __syncthreads();
            if (t == 0) {
                atomicAdd(&bar[r], 1);
                int spins = 0;
                while (atomicAdd(&bar[r], 0) < NB && spins < 100000) ++spins;
            }
            __syncthreads();
        }
    }
    float4 bb = reinterpret_cast<const float4*>(bias)[c4];
    if (n0 < NN) {
        float dd = dis[n0];
        float4 v = make_float4(dd * a0.x + bb.x, dd * a0.y + bb.y,
                               dd * a0.z + bb.z, dd * a0.w + bb.w);
        if (relu) { v.x = fmaxf(v.x, 0.f); v.y = fmaxf(v.y, 0.f);
                    v.z = fmaxf(v.z, 0.f); v.w = fmaxf(v.w, 0.f); }
        buf4[(n0 << 2) + c4] = v;
    }
    if (n1 < NN) {
        float dd = dis[n1];
        float4 v = make_float4(dd * a1.x + bb.x, dd * a1.y + bb.y,
                               dd * a1.z + bb.z, dd * a1.w + bb.w);
        if (relu) { v.x = fmaxf(v.x, 0.f); v.y = fmaxf(v.y, 0.f);
                    v.z = fmaxf(v.z, 0.f); v.w = fmaxf(v.w, 0.f); }
        buf4[(n1 << 2) + c4] = v;
    }
}

// conv2: one thread per dst row, float2 registers, fused bias + log_softmax.
__global__ __launch_bounds__(512) void agg2_lsm(const int* __restrict__ pedge2,
                                                const int* __restrict__ rowStart,
                                                const float* __restrict__ xs,
                                                const float* __restrict__ dis,
                                                const float* __restrict__ bias,
                                                float* __restrict__ out) {
    int t = threadIdx.x;
    int b = blockIdx.x;
    int node = (b << BSH) + t;
    if (node >= NN) return;
    const float2* xs2 = reinterpret_cast<const float2*>(xs);
    float a0 = 0.f, a1 = 0.f;
    for (int s = 0; s < NCH; ++s) {
        const int* rs = rowStart + (size_t)(b * NCH + s) * BSZ;
        int e0 = rs[t], e1 = rs[t + 1];
        for (int e = e0; e < e1; ++e) {
            float2 v = xs2[pedge2[e]];
            a0 += v.x; a1 += v.y;
        }
    }
    float2 sv = xs2[node];
    float d = dis[node];
    float v0 = (a0 + sv.x) * d + bias[0];
    float v1 = (a1 + sv.y) * d + bias[1];
    float m = fmaxf(v0, v1);
    float lse = m + logf(__expf(v0 - m) + __expf(v1 - m));
    reinterpret_cast<float2*>(out)[node] = make_float2(v0 - lse, v1 - lse);
}

// ---------------- launch ----------------

extern "C" void kernel_launch(void* const* d_in, const int* in_sizes, int n_in,
                              void* d_out, int out_size, void* d_ws, size_t ws_size,
                              hipStream_t stream) {
    const float* x = (const float*)d_in[0];
    const int* ei = (const int*)d_in[1];
    const float* W1 = (const float*)d_in[2];
    const float* b1 = (const float*)d_in[3];
    const float* W3 = (const float*)d_in[4];
    const float* b3 = (const float*)d_in[5];
    const float* W2 = (const float*)d_in[6];
    const float* b2 = (const float*)d_in[7];
    float* out = (float*)d_out;

    const int* src = ei;       // edge_index[0]
    const int* dst = ei + NE;  // edge_index[1]

    // workspace layout (~62 MB). bufA aliases pedge (dead after subsort).
    int* W = (int*)d_ws;
    unsigned* pedge = (unsigned*)W;                        // NE
    int* pedge2 = W + NE;                                  // NE
    int* rowStart = W + 2 * (size_t)NE;                    // NK*BSZ + 4
    int* blockHist = rowStart + (size_t)NK * BSZ + 4;      // PB*NK
    int* chunkStart = blockHist + (size_t)PB * NK;         // NK + 4
    float* dis = (float*)(chunkStart + NK + 4);            // NN
    float* bufB = dis + NN;                                // NN*HID
    int* bar = (int*)(bufB + (size_t)NN * HID);            // 16
    float* bufA = (float*)W;                               // aliases pedge

    const int B = 256;
    auto cdiv = [](long long a, long long b) { return (int)((a + b - 1) / b); };

    hipMemsetAsync(bar, 0, 16 * sizeof(int), stream);

    // partition: (bucket,slice) sort -> within-segment dst sort -> CSR + dis
    hist_pass<<<PB, PT, 0, stream>>>(src, dst, blockHist);
    tot_pass<<<cdiv(NK, 256), 256, 0, stream>>>(blockHist, chunkStart);
    scan_keys<<<1, 1024, 0, stream>>>(chunkStart);
    offsets_pass<<<cdiv(NK, 256), 256, 0, stream>>>(blockHist, chunkStart);
    scatter_pass<<<PB, PT, 0, stream>>>(src, dst, blockHist, pedge);
    subsort<<<NB, 512, 0, stream>>>(pedge, chunkStart, pedge2, rowStart, dis);

    // conv1: bufA = (x@W1)*dis ; fused 8-slice aggregation into bufB
    gemm_x_w1<<<NN / GXR, B, 0, stream>>>(x, W1, dis, bufA);
    agg16_all<<<NB, 1024, 0, stream>>>(pedge2, rowStart, bufA, dis, b1, bufB, 1, bar);

    // conv3
    gemm_h_w16<<<cdiv(NN, 16), B, 0, stream>>>(bufB, W3, dis, bufA);
    agg16_all<<<NB, 1024, 0, stream>>>(pedge2, rowStart, bufA, dis, b3, bufB, 1, bar + 8);

    // conv2 + log_softmax
    gemm_h_w2<<<cdiv((long long)NN * DOUT, B), B, 0, stream>>>(bufB, W2, dis, bufA);
    agg2_lsm<<<NB, 512, 0, stream>>>(pedge2, rowStart, bufA, dis, b2, out);
}

// Round 11
// 732.148 us; speedup vs baseline: 1.0766x; 1.0766x over previous
//
#include <hip/hip_runtime.h>

#define NN 200000
#define NE 5000000
#define DIN 128
#define HID 16
#define DOUT 2
#define BSH 9            // dst-buckets of 512 nodes
#define BSZ 512
#define NB 391           // ceil(NN/512)
#define NCH 8            // src slices of 25000 nodes (1.6 MB of xs' @ HID=16)
#define SLICE_DIV 25000
#define NK (NB * NCH)    // 3128 sort keys
#define PB 256           // partition grid blocks
#define PT 512           // partition block threads
#define CAP 4096         // max edges per (bucket,slice) segment; mean 1599

static_assert((NN + BSZ - 1) / BSZ == NB, "bucket count");
static_assert((NN - 1) / SLICE_DIV == NCH - 1, "slice count");

// ---------------- stage 1: counting sort by (dst>>9, src/25000) ----------------

__global__ __launch_bounds__(PT) void hist_pass(const int* __restrict__ src,
                                                const int* __restrict__ dst,
                                                int* __restrict__ blockHist) {
    __shared__ int h[NK];  // 12.5 KB
    for (int k = threadIdx.x; k < NK; k += PT) h[k] = 0;
    __syncthreads();
    for (int i = blockIdx.x * PT + threadIdx.x; i < NE; i += PB * PT) {
        int dv = __builtin_nontemporal_load(dst + i);
        int sv = __builtin_nontemporal_load(src + i);
        atomicAdd(&h[((dv >> BSH) << 3) + sv / SLICE_DIV], 1);
    }
    __syncthreads();
    for (int k = threadIdx.x; k < NK; k += PT)
        blockHist[(size_t)blockIdx.x * NK + k] = h[k];
}

// per-key totals -> chunkStart[k] (unscanned)
__global__ __launch_bounds__(256) void tot_pass(const int* __restrict__ blockHist,
                                                int* __restrict__ chunkStart) {
    int k = blockIdx.x * 256 + threadIdx.x;
    if (k >= NK) return;
    int s = 0;
#pragma unroll 8
    for (int b = 0; b < PB; ++b) s += blockHist[(size_t)b * NK + k];
    chunkStart[k] = s;
}

// exclusive scan of chunkStart[0..NK) in place (single block)
__global__ __launch_bounds__(1024) void scan_keys(int* __restrict__ chunkStart) {
    __shared__ int psum[1024];
    int t = threadIdx.x;
    const int KPT = (NK + 1023) / 1024;  // 4
    int k0 = t * KPT; if (k0 > NK) k0 = NK;
    int k1 = k0 + KPT; if (k1 > NK) k1 = NK;
    int vals[4];
    int s = 0;
    for (int k = k0; k < k1; ++k) { vals[k - k0] = chunkStart[k]; s += vals[k - k0]; }
    psum[t] = s;
    __syncthreads();
    for (int off = 1; off < 1024; off <<= 1) {
        int add = (t >= off) ? psum[t - off] : 0;
        __syncthreads();
        psum[t] += add;
        __syncthreads();
    }
    int run = psum[t] - s;
    for (int k = k0; k < k1; ++k) { chunkStart[k] = run; run += vals[k - k0]; }
    if (t == 0) chunkStart[NK] = NE;
}

// per-(key, block) exclusive offsets into blockHist
__global__ __launch_bounds__(256) void offsets_pass(int* __restrict__ blockHist,
                                                    const int* __restrict__ chunkStart) {
    int k = blockIdx.x * 256 + threadIdx.x;
    if (k >= NK) return;
    int r = chunkStart[k];
#pragma unroll 8
    for (int b = 0; b < PB; ++b) {
        size_t idx = (size_t)b * NK + k;
        int v = blockHist[idx];
        blockHist[idx] = r;
        r += v;
    }
}

__global__ __launch_bounds__(PT) void scatter_pass(const int* __restrict__ src,
                                                   const int* __restrict__ dst,
                                                   const int* __restrict__ blockHist,
                                                   unsigned* __restrict__ pedge) {
    __shared__ int cur[NK];  // 12.5 KB
    for (int k = threadIdx.x; k < NK; k += PT)
        cur[k] = blockHist[(size_t)blockIdx.x * NK + k];
    __syncthreads();
    // MUST traverse edges in the same per-block order as hist_pass
    for (int i = blockIdx.x * PT + threadIdx.x; i < NE; i += PB * PT) {
        int sv = __builtin_nontemporal_load(src + i);
        int dv = __builtin_nontemporal_load(dst + i);
        int key = ((dv >> BSH) << 3) + sv / SLICE_DIV;
        int pos = atomicAdd(&cur[key], 1);  // LDS atomic only
        pedge[pos] = ((unsigned)sv << BSH) | (unsigned)(dv & (BSZ - 1));
    }
}

// ---------------- stage 2: within-segment sort by dst -> CSR (one-time) ----------------

__global__ __launch_bounds__(512) void subsort(const unsigned* __restrict__ pedge,
                                               const int* __restrict__ chunkStart,
                                               int* __restrict__ pedge2,
                                               int* __restrict__ rowStart,
                                               float* __restrict__ dis) {
    __shared__ unsigned ebuf[CAP];  // 16 KB
    __shared__ int hist[BSZ];
    __shared__ int cur[BSZ];
    __shared__ int wsum[8];
    int t = threadIdx.x;
    int b = blockIdx.x;
    int lane = t & 63, w = t >> 6;
    int deg = 1;  // self loop
    for (int s = 0; s < NCH; ++s) {
        int seg = b * NCH + s;
        int e0 = chunkStart[seg], e1 = chunkStart[seg + 1];
        int n = e1 - e0;
        hist[t] = 0;
        __syncthreads();
        for (int i = t; i < n; i += 512) {
            unsigned p = __builtin_nontemporal_load(pedge + e0 + i);
            ebuf[i] = p;
            atomicAdd(&hist[p & (BSZ - 1u)], 1);
        }
        __syncthreads();
        int v = hist[t];
        deg += v;
        int inc = v;  // wave-inclusive scan
        for (int off = 1; off < 64; off <<= 1) {
            int nb = __shfl_up(inc, off, 64);
            if (lane >= off) inc += nb;
        }
        if (lane == 63) wsum[w] = inc;
        __syncthreads();
        if (t == 0) {
            int car = 0;
#pragma unroll
            for (int i = 0; i < 8; ++i) { int u = wsum[i]; wsum[i] = car; car += u; }
        }
        __syncthreads();
        int excl = inc - v + wsum[w];
        rowStart[(size_t)seg * BSZ + t] = e0 + excl;
        cur[t] = excl;
        __syncthreads();
        for (int i = t; i < n; i += 512) {
            unsigned p = ebuf[i];
            int pos = atomicAdd(&cur[p & (BSZ - 1u)], 1);
            pedge2[e0 + pos] = (int)(p >> BSH);
        }
        __syncthreads();
    }
    int node = (b << BSH) + t;
    if (node < NN) dis[node] = rsqrtf((float)deg);
    if (b == 0 && t == 0) rowStart[(size_t)NK * BSZ] = NE;
}

// ---------------- dense GEMMs, epilogue-scaled by dis[row] (xs' = (h@W)*dis) ----------------

#define GXR 64
#define XPAD 132
__global__ __launch_bounds__(256) void gemm_x_w1(const float* __restrict__ x,
                                                 const float* __restrict__ W,
                                                 const float* __restrict__ dis,
                                                 float* __restrict__ out) {
    __shared__ float w[DIN * HID];     // 8 KB
    __shared__ float xt[GXR * XPAD];   // 33 KB
    int t = threadIdx.x;
    for (int i = t; i < DIN * HID; i += 256) w[i] = W[i];
    int rbase = blockIdx.x * GXR;  // NN = 3125 * 64, no tail
    const float4* xg = reinterpret_cast<const float4*>(x + (size_t)rbase * DIN);
    float4* xt4 = reinterpret_cast<float4*>(xt);
    for (int i = t; i < GXR * (DIN / 4); i += 256) {
        int row = i >> 5, kk = i & 31;
        xt4[row * (XPAD / 4) + kk] = xg[i];
    }
    __syncthreads();
    int row = t >> 2;
    int c0 = (t & 3) * 4;
    const float* xr = xt + row * XPAD;
    float ax = 0.f, ay = 0.f, az = 0.f, aw = 0.f;
#pragma unroll 4
    for (int k = 0; k < DIN; ++k) {
        float xv = xr[k];
        float4 wv = *reinterpret_cast<const float4*>(&w[k * HID + c0]);
        ax += xv * wv.x; ay += xv * wv.y; az += xv * wv.z; aw += xv * wv.w;
    }
    int node = rbase + row;
    float dd = dis[node];
    *reinterpret_cast<float4*>(&out[(size_t)node * HID + c0]) =
        make_float4(ax * dd, ay * dd, az * dd, aw * dd);
}

__global__ __launch_bounds__(256) void gemm_h_w16(const float* __restrict__ h,
                                                  const float* __restrict__ W,
                                                  const float* __restrict__ dis,
                                                  float* __restrict__ out) {
    __shared__ float w[HID * HID];
    if (threadIdx.x < HID * HID) w[threadIdx.x] = W[threadIdx.x];
    __syncthreads();
    int row = blockIdx.x * 16 + (threadIdx.x >> 4);
    int c = threadIdx.x & 15;
    if (row >= NN) return;
    const float4* hr = reinterpret_cast<const float4*>(h + (size_t)row * HID);
    float acc = 0.f;
#pragma unroll
    for (int k4 = 0; k4 < HID / 4; ++k4) {
        float4 v = hr[k4];
        acc += v.x * w[(4 * k4 + 0) * HID + c] + v.y * w[(4 * k4 + 1) * HID + c]
             + v.z * w[(4 * k4 + 2) * HID + c] + v.w * w[(4 * k4 + 3) * HID + c];
    }
    out[row * HID + c] = acc * dis[row];
}

__global__ __launch_bounds__(256) void gemm_h_w2(const float* __restrict__ h,
                                                 const float* __restrict__ W,
                                                 const float* __restrict__ dis,
                                                 float* __restrict__ out) {
    int t = blockIdx.x * 256 + threadIdx.x;
    int row = t >> 1;
    int c = t & 1;
    if (row >= NN) return;
    const float* hr = h + (size_t)row * HID;
    float acc = 0.f;
#pragma unroll
    for (int k = 0; k < HID; ++k) acc += hr[k] * W[k * DOUT + c];
    out[row * DOUT + c] = acc * dis[row];
}

// ---------------- aggregation: one fused kernel per conv, register accumulators ----------------
// 391 blocks x 1024 thr, no LDS, ~20 VGPR -> 2 blocks/CU -> ALL blocks co-resident.
// Soft slice-alignment barrier: arrival = ONE atomicAdd per block; polling =
// coherent atomic LOAD (no RMW serialization) paced by s_sleep. Spin-capped:
// purely a timing fence, correctness never depends on it.

__device__ __forceinline__ void acc_edges(const int* __restrict__ pedge2,
                                          const float4* __restrict__ xs4,
                                          int e0, int e1, int c4, float4& a) {
    int e = e0;
    for (; e + 1 < e1; e += 2) {
        int s0 = __builtin_nontemporal_load(pedge2 + e);
        int s1 = __builtin_nontemporal_load(pedge2 + e + 1);
        float4 u = xs4[(s0 << 2) + c4];
        float4 w = xs4[(s1 << 2) + c4];
        a.x += u.x + w.x; a.y += u.y + w.y; a.z += u.z + w.z; a.w += u.w + w.w;
    }
    if (e < e1) {
        float4 u = xs4[(__builtin_nontemporal_load(pedge2 + e) << 2) + c4];
        a.x += u.x; a.y += u.y; a.z += u.z; a.w += u.w;
    }
}

__global__ __launch_bounds__(1024, 8) void agg16_all(const int* __restrict__ pedge2,
                                                     const int* __restrict__ rowStart,
                                                     const float* __restrict__ xs,
                                                     const float* __restrict__ dis,
                                                     const float* __restrict__ bias,
                                                     float* __restrict__ buf,
                                                     int relu, int* bar) {
    int t = threadIdx.x;
    int b = blockIdx.x;
    int base = b << BSH;
    int c4 = t & 3;
    int g = t >> 2;  // rows g and g+256 of this bucket
    const float4* xs4 = reinterpret_cast<const float4*>(xs);
    float4* buf4 = reinterpret_cast<float4*>(buf);
    int n0 = base + g, n1 = base + g + 256;
    float4 a0 = make_float4(0.f, 0.f, 0.f, 0.f);
    float4 a1 = make_float4(0.f, 0.f, 0.f, 0.f);
    if (n0 < NN) a0 = xs4[(n0 << 2) + c4];  // self-loop term
    if (n1 < NN) a1 = xs4[(n1 << 2) + c4];
    for (int r = 0; r < NCH; ++r) {
        const int* rs = rowStart + (size_t)(b * NCH + r) * BSZ;
        acc_edges(pedge2, xs4, rs[g], rs[g + 1], c4, a0);
        acc_edges(pedge2, xs4, rs[g + 256], rs[g + 257], c4, a1);
        if (r < NCH - 1) {  // soft slice-alignment barrier
            __syncthreads();
            if (t == 0) {
                __hip_atomic_fetch_add(&bar[r], 1, __ATOMIC_RELAXED,
                                       __HIP_MEMORY_SCOPE_AGENT);
                int spins = 0;
                while (__hip_atomic_load(&bar[r], __ATOMIC_RELAXED,
                                         __HIP_MEMORY_SCOPE_AGENT) < NB &&
                       spins < 10000) {
                    __builtin_amdgcn_s_sleep(16);
                    ++spins;
                }
            }
            __syncthreads();
        }
    }
    float4 bb = reinterpret_cast<const float4*>(bias)[c4];
    if (n0 < NN) {
        float dd = dis[n0];
        float4 v = make_float4(dd * a0.x + bb.x, dd * a0.y + bb.y,
                               dd * a0.z + bb.z, dd * a0.w + bb.w);
        if (relu) { v.x = fmaxf(v.x, 0.f); v.y = fmaxf(v.y, 0.f);
                    v.z = fmaxf(v.z, 0.f); v.w = fmaxf(v.w, 0.f); }
        buf4[(n0 << 2) + c4] = v;
    }
    if (n1 < NN) {
        float dd = dis[n1];
        float4 v = make_float4(dd * a1.x + bb.x, dd * a1.y + bb.y,
                               dd * a1.z + bb.z, dd * a1.w + bb.w);
        if (relu) { v.x = fmaxf(v.x, 0.f); v.y = fmaxf(v.y, 0.f);
                    v.z = fmaxf(v.z, 0.f); v.w = fmaxf(v.w, 0.f); }
        buf4[(n1 << 2) + c4] = v;
    }
}

// conv2: one thread per dst row, float2 registers, fused bias + log_softmax.
__global__ __launch_bounds__(512) void agg2_lsm(const int* __restrict__ pedge2,
                                                const int* __restrict__ rowStart,
                                                const float* __restrict__ xs,
                                                const float* __restrict__ dis,
                                                const float* __restrict__ bias,
                                                float* __restrict__ out) {
    int t = threadIdx.x;
    int b = blockIdx.x;
    int node = (b << BSH) + t;
    if (node >= NN) return;
    const float2* xs2 = reinterpret_cast<const float2*>(xs);
    float a0 = 0.f, a1 = 0.f;
    for (int s = 0; s < NCH; ++s) {
        const int* rs = rowStart + (size_t)(b * NCH + s) * BSZ;
        int e0 = rs[t], e1 = rs[t + 1];
        for (int e = e0; e < e1; ++e) {
            float2 v = xs2[pedge2[e]];
            a0 += v.x; a1 += v.y;
        }
    }
    float2 sv = xs2[node];
    float d = dis[node];
    float v0 = (a0 + sv.x) * d + bias[0];
    float v1 = (a1 + sv.y) * d + bias[1];
    float m = fmaxf(v0, v1);
    float lse = m + logf(__expf(v0 - m) + __expf(v1 - m));
    reinterpret_cast<float2*>(out)[node] = make_float2(v0 - lse, v1 - lse);
}

// ---------------- launch ----------------

extern "C" void kernel_launch(void* const* d_in, const int* in_sizes, int n_in,
                              void* d_out, int out_size, void* d_ws, size_t ws_size,
                              hipStream_t stream) {
    const float* x = (const float*)d_in[0];
    const int* ei = (const int*)d_in[1];
    const float* W1 = (const float*)d_in[2];
    const float* b1 = (const float*)d_in[3];
    const float* W3 = (const float*)d_in[4];
    const float* b3 = (const float*)d_in[5];
    const float* W2 = (const float*)d_in[6];
    const float* b2 = (const float*)d_in[7];
    float* out = (float*)d_out;

    const int* src = ei;       // edge_index[0]
    const int* dst = ei + NE;  // edge_index[1]

    // workspace layout (~62 MB). bufA aliases pedge (dead after subsort).
    int* W = (int*)d_ws;
    unsigned* pedge = (unsigned*)W;                        // NE
    int* pedge2 = W + NE;                                  // NE
    int* rowStart = W + 2 * (size_t)NE;                    // NK*BSZ + 4
    int* blockHist = rowStart + (size_t)NK * BSZ + 4;      // PB*NK
    int* chunkStart = blockHist + (size_t)PB * NK;         // NK + 4
    float* dis = (float*)(chunkStart + NK + 4);            // NN
    float* bufB = dis + NN;                                // NN*HID
    int* bar = (int*)(bufB + (size_t)NN * HID);            // 16
    float* bufA = (float*)W;                               // aliases pedge

    const int B = 256;
    auto cdiv = [](long long a, long long b) { return (int)((a + b - 1) / b); };

    hipMemsetAsync(bar, 0, 16 * sizeof(int), stream);

    // partition: (bucket,slice) sort -> within-segment dst sort -> CSR + dis
    hist_pass<<<PB, PT, 0, stream>>>(src, dst, blockHist);
    tot_pass<<<cdiv(NK, 256), 256, 0, stream>>>(blockHist, chunkStart);
    scan_keys<<<1, 1024, 0, stream>>>(chunkStart);
    offsets_pass<<<cdiv(NK, 256), 256, 0, stream>>>(blockHist, chunkStart);
    scatter_pass<<<PB, PT, 0, stream>>>(src, dst, blockHist, pedge);
    subsort<<<NB, 512, 0, stream>>>(pedge, chunkStart, pedge2, rowStart, dis);

    // conv1: bufA = (x@W1)*dis ; fused 8-slice aggregation into bufB
    gemm_x_w1<<<NN / GXR, B, 0, stream>>>(x, W1, dis, bufA);
    agg16_all<<<NB, 1024, 0, stream>>>(pedge2, rowStart, bufA, dis, b1, bufB, 1, bar);

    // conv3
    gemm_h_w16<<<cdiv(NN, 16), B, 0, stream>>>(bufB, W3, dis, bufA);
    agg16_all<<<NB, 1024, 0, stream>>>(pedge2, rowStart, bufA, dis, b3, bufB, 1, bar + 8);

    // conv2 + log_softmax
    gemm_h_w2<<<cdiv((long long)NN * DOUT, B), B, 0, stream>>>(bufB, W2, dis, bufA);
    agg2_lsm<<<NB, 512, 0, stream>>>(pedge2, rowStart, bufA, dis, b2, out);
}

// Round 12
// 427.238 us; speedup vs baseline: 1.8450x; 1.7137x over previous
//
#include <hip/hip_runtime.h>

#define NN 200000
#define NE 5000000
#define DIN 128
#define HID 16
#define DOUT 2
#define BSH 9            // dst-buckets of 512 nodes
#define BSZ 512
#define NB 391           // ceil(NN/512)
#define NCH 8            // src slices of 25000 nodes (1.6 MB of xs' @ HID=16)
#define SLICE_DIV 25000
#define NK (NB * NCH)    // 3128 sort keys
#define PB 256           // partition grid blocks
#define PT 512           // partition block threads
#define CAP 4096         // max edges per (bucket,slice) segment; mean 1599

static_assert((NN + BSZ - 1) / BSZ == NB, "bucket count");
static_assert((NN - 1) / SLICE_DIV == NCH - 1, "slice count");

// ---------------- stage 1: counting sort by (dst>>9, src/25000) ----------------

__global__ __launch_bounds__(PT) void hist_pass(const int* __restrict__ src,
                                                const int* __restrict__ dst,
                                                int* __restrict__ blockHist) {
    __shared__ int h[NK];  // 12.5 KB
    for (int k = threadIdx.x; k < NK; k += PT) h[k] = 0;
    __syncthreads();
    for (int i = blockIdx.x * PT + threadIdx.x; i < NE; i += PB * PT) {
        int dv = __builtin_nontemporal_load(dst + i);
        int sv = __builtin_nontemporal_load(src + i);
        atomicAdd(&h[((dv >> BSH) << 3) + sv / SLICE_DIV], 1);
    }
    __syncthreads();
    for (int k = threadIdx.x; k < NK; k += PT)
        blockHist[(size_t)blockIdx.x * NK + k] = h[k];
}

// per-key totals -> chunkStart[k] (unscanned)
__global__ __launch_bounds__(256) void tot_pass(const int* __restrict__ blockHist,
                                                int* __restrict__ chunkStart) {
    int k = blockIdx.x * 256 + threadIdx.x;
    if (k >= NK) return;
    int s = 0;
#pragma unroll 8
    for (int b = 0; b < PB; ++b) s += blockHist[(size_t)b * NK + k];
    chunkStart[k] = s;
}

// exclusive scan of chunkStart[0..NK) in place (single block)
__global__ __launch_bounds__(1024) void scan_keys(int* __restrict__ chunkStart) {
    __shared__ int psum[1024];
    int t = threadIdx.x;
    const int KPT = (NK + 1023) / 1024;  // 4
    int k0 = t * KPT; if (k0 > NK) k0 = NK;
    int k1 = k0 + KPT; if (k1 > NK) k1 = NK;
    int vals[4];
    int s = 0;
    for (int k = k0; k < k1; ++k) { vals[k - k0] = chunkStart[k]; s += vals[k - k0]; }
    psum[t] = s;
    __syncthreads();
    for (int off = 1; off < 1024; off <<= 1) {
        int add = (t >= off) ? psum[t - off] : 0;
        __syncthreads();
        psum[t] += add;
        __syncthreads();
    }
    int run = psum[t] - s;
    for (int k = k0; k < k1; ++k) { chunkStart[k] = run; run += vals[k - k0]; }
    if (t == 0) chunkStart[NK] = NE;
}

// per-(key, block) exclusive offsets into blockHist
__global__ __launch_bounds__(256) void offsets_pass(int* __restrict__ blockHist,
                                                    const int* __restrict__ chunkStart) {
    int k = blockIdx.x * 256 + threadIdx.x;
    if (k >= NK) return;
    int r = chunkStart[k];
#pragma unroll 8
    for (int b = 0; b < PB; ++b) {
        size_t idx = (size_t)b * NK + k;
        int v = blockHist[idx];
        blockHist[idx] = r;
        r += v;
    }
}

__global__ __launch_bounds__(PT) void scatter_pass(const int* __restrict__ src,
                                                   const int* __restrict__ dst,
                                                   const int* __restrict__ blockHist,
                                                   unsigned* __restrict__ pedge) {
    __shared__ int cur[NK];  // 12.5 KB
    for (int k = threadIdx.x; k < NK; k += PT)
        cur[k] = blockHist[(size_t)blockIdx.x * NK + k];
    __syncthreads();
    // MUST traverse edges in the same per-block order as hist_pass
    for (int i = blockIdx.x * PT + threadIdx.x; i < NE; i += PB * PT) {
        int sv = __builtin_nontemporal_load(src + i);
        int dv = __builtin_nontemporal_load(dst + i);
        int key = ((dv >> BSH) << 3) + sv / SLICE_DIV;
        int pos = atomicAdd(&cur[key], 1);  // LDS atomic only
        pedge[pos] = ((unsigned)sv << BSH) | (unsigned)(dv & (BSZ - 1));
    }
}

// ---------------- stage 2: within-segment sort by dst -> CSR (one-time) ----------------

__global__ __launch_bounds__(512) void subsort(const unsigned* __restrict__ pedge,
                                               const int* __restrict__ chunkStart,
                                               int* __restrict__ pedge2,
                                               int* __restrict__ rowStart,
                                               float* __restrict__ dis) {
    __shared__ unsigned ebuf[CAP];  // 16 KB
    __shared__ int hist[BSZ];
    __shared__ int cur[BSZ];
    __shared__ int wsum[8];
    int t = threadIdx.x;
    int b = blockIdx.x;
    int lane = t & 63, w = t >> 6;
    int deg = 1;  // self loop
    for (int s = 0; s < NCH; ++s) {
        int seg = b * NCH + s;
        int e0 = chunkStart[seg], e1 = chunkStart[seg + 1];
        int n = e1 - e0;
        hist[t] = 0;
        __syncthreads();
        for (int i = t; i < n; i += 512) {
            unsigned p = __builtin_nontemporal_load(pedge + e0 + i);
            ebuf[i] = p;
            atomicAdd(&hist[p & (BSZ - 1u)], 1);
        }
        __syncthreads();
        int v = hist[t];
        deg += v;
        int inc = v;  // wave-inclusive scan
        for (int off = 1; off < 64; off <<= 1) {
            int nb = __shfl_up(inc, off, 64);
            if (lane >= off) inc += nb;
        }
        if (lane == 63) wsum[w] = inc;
        __syncthreads();
        if (t == 0) {
            int car = 0;
#pragma unroll
            for (int i = 0; i < 8; ++i) { int u = wsum[i]; wsum[i] = car; car += u; }
        }
        __syncthreads();
        int excl = inc - v + wsum[w];
        rowStart[(size_t)seg * BSZ + t] = e0 + excl;
        cur[t] = excl;
        __syncthreads();
        for (int i = t; i < n; i += 512) {
            unsigned p = ebuf[i];
            int pos = atomicAdd(&cur[p & (BSZ - 1u)], 1);
            pedge2[e0 + pos] = (int)(p >> BSH);
        }
        __syncthreads();
    }
    int node = (b << BSH) + t;
    if (node < NN) dis[node] = rsqrtf((float)deg);
    if (b == 0 && t == 0) rowStart[(size_t)NK * BSZ] = NE;
}

// ---------------- dense GEMMs, epilogue-scaled by dis[row] (xs' = (h@W)*dis) ----------------

#define GXR 64
#define XPAD 132
__global__ __launch_bounds__(256) void gemm_x_w1(const float* __restrict__ x,
                                                 const float* __restrict__ W,
                                                 const float* __restrict__ dis,
                                                 float* __restrict__ out) {
    __shared__ float w[DIN * HID];     // 8 KB
    __shared__ float xt[GXR * XPAD];   // 33 KB
    int t = threadIdx.x;
    for (int i = t; i < DIN * HID; i += 256) w[i] = W[i];
    int rbase = blockIdx.x * GXR;  // NN = 3125 * 64, no tail
    const float4* xg = reinterpret_cast<const float4*>(x + (size_t)rbase * DIN);
    float4* xt4 = reinterpret_cast<float4*>(xt);
    for (int i = t; i < GXR * (DIN / 4); i += 256) {
        int row = i >> 5, kk = i & 31;
        xt4[row * (XPAD / 4) + kk] = xg[i];
    }
    __syncthreads();
    int row = t >> 2;
    int c0 = (t & 3) * 4;
    const float* xr = xt + row * XPAD;
    float ax = 0.f, ay = 0.f, az = 0.f, aw = 0.f;
#pragma unroll 4
    for (int k = 0; k < DIN; ++k) {
        float xv = xr[k];
        float4 wv = *reinterpret_cast<const float4*>(&w[k * HID + c0]);
        ax += xv * wv.x; ay += xv * wv.y; az += xv * wv.z; aw += xv * wv.w;
    }
    int node = rbase + row;
    float dd = dis[node];
    *reinterpret_cast<float4*>(&out[(size_t)node * HID + c0]) =
        make_float4(ax * dd, ay * dd, az * dd, aw * dd);
}

__global__ __launch_bounds__(256) void gemm_h_w16(const float* __restrict__ h,
                                                  const float* __restrict__ W,
                                                  const float* __restrict__ dis,
                                                  float* __restrict__ out) {
    __shared__ float w[HID * HID];
    if (threadIdx.x < HID * HID) w[threadIdx.x] = W[threadIdx.x];
    __syncthreads();
    int row = blockIdx.x * 16 + (threadIdx.x >> 4);
    int c = threadIdx.x & 15;
    if (row >= NN) return;
    const float4* hr = reinterpret_cast<const float4*>(h + (size_t)row * HID);
    float acc = 0.f;
#pragma unroll
    for (int k4 = 0; k4 < HID / 4; ++k4) {
        float4 v = hr[k4];
        acc += v.x * w[(4 * k4 + 0) * HID + c] + v.y * w[(4 * k4 + 1) * HID + c]
             + v.z * w[(4 * k4 + 2) * HID + c] + v.w * w[(4 * k4 + 3) * HID + c];
    }
    out[row * HID + c] = acc * dis[row];
}

__global__ __launch_bounds__(256) void gemm_h_w2(const float* __restrict__ h,
                                                 const float* __restrict__ W,
                                                 const float* __restrict__ dis,
                                                 float* __restrict__ out) {
    int t = blockIdx.x * 256 + threadIdx.x;
    int row = t >> 1;
    int c = t & 1;
    if (row >= NN) return;
    const float* hr = h + (size_t)row * HID;
    float acc = 0.f;
#pragma unroll
    for (int k = 0; k < HID; ++k) acc += hr[k] * W[k * DOUT + c];
    out[row * DOUT + c] = acc * dis[row];
}

// ---------------- aggregation: fused per conv, register accumulators, NO barrier ----------------
// Clean A/B vs R11: identical kernel minus the inter-slice barrier. Blocks walk
// slices 0..7 in the same order; temporal drift trades some L2 hits (FETCH up)
// for zero sync overhead. buf is written exactly once (no RMW traffic).

__device__ __forceinline__ void acc_edges(const int* __restrict__ pedge2,
                                          const float4* __restrict__ xs4,
                                          int e0, int e1, int c4, float4& a) {
    int e = e0;
    for (; e + 1 < e1; e += 2) {
        int s0 = __builtin_nontemporal_load(pedge2 + e);
        int s1 = __builtin_nontemporal_load(pedge2 + e + 1);
        float4 u = xs4[(s0 << 2) + c4];
        float4 w = xs4[(s1 << 2) + c4];
        a.x += u.x + w.x; a.y += u.y + w.y; a.z += u.z + w.z; a.w += u.w + w.w;
    }
    if (e < e1) {
        float4 u = xs4[(__builtin_nontemporal_load(pedge2 + e) << 2) + c4];
        a.x += u.x; a.y += u.y; a.z += u.z; a.w += u.w;
    }
}

__global__ __launch_bounds__(1024, 8) void agg16_all(const int* __restrict__ pedge2,
                                                     const int* __restrict__ rowStart,
                                                     const float* __restrict__ xs,
                                                     const float* __restrict__ dis,
                                                     const float* __restrict__ bias,
                                                     float* __restrict__ buf,
                                                     int relu) {
    int t = threadIdx.x;
    int b = blockIdx.x;
    int base = b << BSH;
    int c4 = t & 3;
    int g = t >> 2;  // rows g and g+256 of this bucket
    const float4* xs4 = reinterpret_cast<const float4*>(xs);
    float4* buf4 = reinterpret_cast<float4*>(buf);
    int n0 = base + g, n1 = base + g + 256;
    float4 a0 = make_float4(0.f, 0.f, 0.f, 0.f);
    float4 a1 = make_float4(0.f, 0.f, 0.f, 0.f);
    if (n0 < NN) a0 = xs4[(n0 << 2) + c4];  // self-loop term
    if (n1 < NN) a1 = xs4[(n1 << 2) + c4];
    for (int r = 0; r < NCH; ++r) {
        const int* rs = rowStart + (size_t)(b * NCH + r) * BSZ;
        acc_edges(pedge2, xs4, rs[g], rs[g + 1], c4, a0);
        acc_edges(pedge2, xs4, rs[g + 256], rs[g + 257], c4, a1);
    }
    float4 bb = reinterpret_cast<const float4*>(bias)[c4];
    if (n0 < NN) {
        float dd = dis[n0];
        float4 v = make_float4(dd * a0.x + bb.x, dd * a0.y + bb.y,
                               dd * a0.z + bb.z, dd * a0.w + bb.w);
        if (relu) { v.x = fmaxf(v.x, 0.f); v.y = fmaxf(v.y, 0.f);
                    v.z = fmaxf(v.z, 0.f); v.w = fmaxf(v.w, 0.f); }
        buf4[(n0 << 2) + c4] = v;
    }
    if (n1 < NN) {
        float dd = dis[n1];
        float4 v = make_float4(dd * a1.x + bb.x, dd * a1.y + bb.y,
                               dd * a1.z + bb.z, dd * a1.w + bb.w);
        if (relu) { v.x = fmaxf(v.x, 0.f); v.y = fmaxf(v.y, 0.f);
                    v.z = fmaxf(v.z, 0.f); v.w = fmaxf(v.w, 0.f); }
        buf4[(n1 << 2) + c4] = v;
    }
}

// conv2: one thread per dst row, float2 registers, fused bias + log_softmax.
__global__ __launch_bounds__(512) void agg2_lsm(const int* __restrict__ pedge2,
                                                const int* __restrict__ rowStart,
                                                const float* __restrict__ xs,
                                                const float* __restrict__ dis,
                                                const float* __restrict__ bias,
                                                float* __restrict__ out) {
    int t = threadIdx.x;
    int b = blockIdx.x;
    int node = (b << BSH) + t;
    if (node >= NN) return;
    const float2* xs2 = reinterpret_cast<const float2*>(xs);
    float a0 = 0.f, a1 = 0.f;
    for (int s = 0; s < NCH; ++s) {
        const int* rs = rowStart + (size_t)(b * NCH + s) * BSZ;
        int e0 = rs[t], e1 = rs[t + 1];
        for (int e = e0; e < e1; ++e) {
            float2 v = xs2[pedge2[e]];
            a0 += v.x; a1 += v.y;
        }
    }
    float2 sv = xs2[node];
    float d = dis[node];
    float v0 = (a0 + sv.x) * d + bias[0];
    float v1 = (a1 + sv.y) * d + bias[1];
    float m = fmaxf(v0, v1);
    float lse = m + logf(__expf(v0 - m) + __expf(v1 - m));
    reinterpret_cast<float2*>(out)[node] = make_float2(v0 - lse, v1 - lse);
}

// ---------------- launch ----------------

extern "C" void kernel_launch(void* const* d_in, const int* in_sizes, int n_in,
                              void* d_out, int out_size, void* d_ws, size_t ws_size,
                              hipStream_t stream) {
    const float* x = (const float*)d_in[0];
    const int* ei = (const int*)d_in[1];
    const float* W1 = (const float*)d_in[2];
    const float* b1 = (const float*)d_in[3];
    const float* W3 = (const float*)d_in[4];
    const float* b3 = (const float*)d_in[5];
    const float* W2 = (const float*)d_in[6];
    const float* b2 = (const float*)d_in[7];
    float* out = (float*)d_out;

    const int* src = ei;       // edge_index[0]
    const int* dst = ei + NE;  // edge_index[1]

    // workspace layout (~62 MB). bufA aliases pedge (dead after subsort).
    int* W = (int*)d_ws;
    unsigned* pedge = (unsigned*)W;                        // NE
    int* pedge2 = W + NE;                                  // NE
    int* rowStart = W + 2 * (size_t)NE;                    // NK*BSZ + 4
    int* blockHist = rowStart + (size_t)NK * BSZ + 4;      // PB*NK
    int* chunkStart = blockHist + (size_t)PB * NK;         // NK + 4
    float* dis = (float*)(chunkStart + NK + 4);            // NN
    float* bufB = dis + NN;                                // NN*HID
    float* bufA = (float*)W;                               // aliases pedge

    const int B = 256;
    auto cdiv = [](long long a, long long b) { return (int)((a + b - 1) / b); };

    // partition: (bucket,slice) sort -> within-segment dst sort -> CSR + dis
    hist_pass<<<PB, PT, 0, stream>>>(src, dst, blockHist);
    tot_pass<<<cdiv(NK, 256), 256, 0, stream>>>(blockHist, chunkStart);
    scan_keys<<<1, 1024, 0, stream>>>(chunkStart);
    offsets_pass<<<cdiv(NK, 256), 256, 0, stream>>>(blockHist, chunkStart);
    scatter_pass<<<PB, PT, 0, stream>>>(src, dst, blockHist, pedge);
    subsort<<<NB, 512, 0, stream>>>(pedge, chunkStart, pedge2, rowStart, dis);

    // conv1: bufA = (x@W1)*dis ; fused slice-ordered aggregation into bufB
    gemm_x_w1<<<NN / GXR, B, 0, stream>>>(x, W1, dis, bufA);
    agg16_all<<<NB, 1024, 0, stream>>>(pedge2, rowStart, bufA, dis, b1, bufB, 1);

    // conv3
    gemm_h_w16<<<cdiv(NN, 16), B, 0, stream>>>(bufB, W3, dis, bufA);
    agg16_all<<<NB, 1024, 0, stream>>>(pedge2, rowStart, bufA, dis, b3, bufB, 1);

    // conv2 + log_softmax
    gemm_h_w2<<<cdiv((long long)NN * DOUT, B), B, 0, stream>>>(bufB, W2, dis, bufA);
    agg2_lsm<<<NB, 512, 0, stream>>>(pedge2, rowStart, bufA, dis, b2, out);
}

// Round 13
// 400.851 us; speedup vs baseline: 1.9665x; 1.0658x over previous
//
#include <hip/hip_runtime.h>

#define NN 200000
#define NE 5000000
#define DIN 128
#define HID 16
#define DOUT 2
#define BSH 10           // dst-buckets of 1024 nodes
#define BSZ 1024
#define NB 196           // ceil(NN/1024) -> one block per CU, all co-resident
#define NCH 8            // src slices of 25000 nodes (1.6 MB of xs' @ HID=16)
#define SLICE_DIV 25000
#define NK (NB * NCH)    // 1568 sort keys
#define PB 256           // partition grid blocks
#define PT 512           // partition block threads
#define CAP 5120         // max edges per (bucket,slice) segment; mean 3189, sigma 56

static_assert((NN + BSZ - 1) / BSZ == NB, "bucket count");
static_assert((NN - 1) / SLICE_DIV == NCH - 1, "slice count");

// ---------------- stage 1: counting sort by (dst>>10, src/25000) ----------------

__global__ __launch_bounds__(PT) void hist_pass(const int* __restrict__ src,
                                                const int* __restrict__ dst,
                                                int* __restrict__ blockHist) {
    __shared__ int h[NK];  // 6.3 KB
    for (int k = threadIdx.x; k < NK; k += PT) h[k] = 0;
    __syncthreads();
    for (int i = blockIdx.x * PT + threadIdx.x; i < NE; i += PB * PT) {
        int dv = dst[i];
        int sv = src[i];
        atomicAdd(&h[((dv >> BSH) << 3) + sv / SLICE_DIV], 1);
    }
    __syncthreads();
    for (int k = threadIdx.x; k < NK; k += PT)
        blockHist[(size_t)blockIdx.x * NK + k] = h[k];
}

// per-key totals -> chunkStart[k] (unscanned)
__global__ __launch_bounds__(256) void tot_pass(const int* __restrict__ blockHist,
                                                int* __restrict__ chunkStart) {
    int k = blockIdx.x * 256 + threadIdx.x;
    if (k >= NK) return;
    int s = 0;
#pragma unroll 8
    for (int b = 0; b < PB; ++b) s += blockHist[(size_t)b * NK + k];
    chunkStart[k] = s;
}

// exclusive scan of chunkStart[0..NK) in place (single block)
__global__ __launch_bounds__(1024) void scan_keys(int* __restrict__ chunkStart) {
    __shared__ int psum[1024];
    int t = threadIdx.x;
    const int KPT = (NK + 1023) / 1024;  // 2
    int k0 = t * KPT; if (k0 > NK) k0 = NK;
    int k1 = k0 + KPT; if (k1 > NK) k1 = NK;
    int vals[4];
    int s = 0;
    for (int k = k0; k < k1; ++k) { vals[k - k0] = chunkStart[k]; s += vals[k - k0]; }
    psum[t] = s;
    __syncthreads();
    for (int off = 1; off < 1024; off <<= 1) {
        int add = (t >= off) ? psum[t - off] : 0;
        __syncthreads();
        psum[t] += add;
        __syncthreads();
    }
    int run = psum[t] - s;
    for (int k = k0; k < k1; ++k) { chunkStart[k] = run; run += vals[k - k0]; }
    if (t == 0) chunkStart[NK] = NE;
}

// per-(key, block) exclusive offsets into blockHist
__global__ __launch_bounds__(256) void offsets_pass(int* __restrict__ blockHist,
                                                    const int* __restrict__ chunkStart) {
    int k = blockIdx.x * 256 + threadIdx.x;
    if (k >= NK) return;
    int r = chunkStart[k];
#pragma unroll 8
    for (int b = 0; b < PB; ++b) {
        size_t idx = (size_t)b * NK + k;
        int v = blockHist[idx];
        blockHist[idx] = r;
        r += v;
    }
}

__global__ __launch_bounds__(PT) void scatter_pass(const int* __restrict__ src,
                                                   const int* __restrict__ dst,
                                                   const int* __restrict__ blockHist,
                                                   unsigned* __restrict__ pedge) {
    __shared__ int cur[NK];  // 6.3 KB
    for (int k = threadIdx.x; k < NK; k += PT)
        cur[k] = blockHist[(size_t)blockIdx.x * NK + k];
    __syncthreads();
    // MUST traverse edges in the same per-block order as hist_pass
    for (int i = blockIdx.x * PT + threadIdx.x; i < NE; i += PB * PT) {
        int sv = src[i];
        int dv = dst[i];
        int key = ((dv >> BSH) << 3) + sv / SLICE_DIV;
        int pos = atomicAdd(&cur[key], 1);  // LDS atomic only
        pedge[pos] = ((unsigned)sv << BSH) | (unsigned)(dv & (BSZ - 1));
    }
}

// ---------------- stage 2: within-segment sort by dst -> CSR (one-time) ----------------

__global__ __launch_bounds__(1024) void subsort(const unsigned* __restrict__ pedge,
                                                const int* __restrict__ chunkStart,
                                                int* __restrict__ pedge2,
                                                int* __restrict__ rowStart,
                                                float* __restrict__ dis) {
    __shared__ unsigned ebuf[CAP];  // 20 KB
    __shared__ int hist[BSZ];       // 4 KB
    __shared__ int cur[BSZ];        // 4 KB
    __shared__ int wsum[16];
    int t = threadIdx.x;
    int b = blockIdx.x;
    int lane = t & 63, w = t >> 6;  // 16 waves
    int deg = 1;  // self loop
    for (int s = 0; s < NCH; ++s) {
        int seg = b * NCH + s;
        int e0 = chunkStart[seg], e1 = chunkStart[seg + 1];
        int n = e1 - e0;
        hist[t] = 0;
        __syncthreads();
        for (int i = t; i < n; i += 1024) {
            unsigned p = pedge[e0 + i];
            ebuf[i] = p;
            atomicAdd(&hist[p & (BSZ - 1u)], 1);
        }
        __syncthreads();
        int v = hist[t];
        deg += v;
        int inc = v;  // wave-inclusive scan
        for (int off = 1; off < 64; off <<= 1) {
            int nb = __shfl_up(inc, off, 64);
            if (lane >= off) inc += nb;
        }
        if (lane == 63) wsum[w] = inc;
        __syncthreads();
        if (t == 0) {
            int car = 0;
#pragma unroll
            for (int i = 0; i < 16; ++i) { int u = wsum[i]; wsum[i] = car; car += u; }
        }
        __syncthreads();
        int excl = inc - v + wsum[w];
        rowStart[(size_t)seg * BSZ + t] = e0 + excl;
        cur[t] = excl;
        __syncthreads();
        for (int i = t; i < n; i += 1024) {
            unsigned p = ebuf[i];
            int pos = atomicAdd(&cur[p & (BSZ - 1u)], 1);
            pedge2[e0 + pos] = (int)(p >> BSH);
        }
        __syncthreads();
    }
    int node = (b << BSH) + t;
    if (node < NN) dis[node] = rsqrtf((float)deg);
    if (b == 0 && t == 0) rowStart[(size_t)NK * BSZ] = NE;
}

// ---------------- dense GEMMs, epilogue-scaled by dis[row] (xs' = (h@W)*dis) ----------------

#define GXR 64
#define XPAD 132
__global__ __launch_bounds__(256) void gemm_x_w1(const float* __restrict__ x,
                                                 const float* __restrict__ W,
                                                 const float* __restrict__ dis,
                                                 float* __restrict__ out) {
    __shared__ float w[DIN * HID];     // 8 KB
    __shared__ float xt[GXR * XPAD];   // 33 KB
    int t = threadIdx.x;
    for (int i = t; i < DIN * HID; i += 256) w[i] = W[i];
    int rbase = blockIdx.x * GXR;  // NN = 3125 * 64, no tail
    const float4* xg = reinterpret_cast<const float4*>(x + (size_t)rbase * DIN);
    float4* xt4 = reinterpret_cast<float4*>(xt);
    for (int i = t; i < GXR * (DIN / 4); i += 256) {
        int row = i >> 5, kk = i & 31;
        xt4[row * (XPAD / 4) + kk] = xg[i];
    }
    __syncthreads();
    int row = t >> 2;
    int c0 = (t & 3) * 4;
    const float* xr = xt + row * XPAD;
    float ax = 0.f, ay = 0.f, az = 0.f, aw = 0.f;
#pragma unroll 4
    for (int k = 0; k < DIN; ++k) {
        float xv = xr[k];
        float4 wv = *reinterpret_cast<const float4*>(&w[k * HID + c0]);
        ax += xv * wv.x; ay += xv * wv.y; az += xv * wv.z; aw += xv * wv.w;
    }
    int node = rbase + row;
    float dd = dis[node];
    *reinterpret_cast<float4*>(&out[(size_t)node * HID + c0]) =
        make_float4(ax * dd, ay * dd, az * dd, aw * dd);
}

__global__ __launch_bounds__(256) void gemm_h_w16(const float* __restrict__ h,
                                                  const float* __restrict__ W,
                                                  const float* __restrict__ dis,
                                                  float* __restrict__ out) {
    __shared__ float w[HID * HID];
    if (threadIdx.x < HID * HID) w[threadIdx.x] = W[threadIdx.x];
    __syncthreads();
    int row = blockIdx.x * 16 + (threadIdx.x >> 4);
    int c = threadIdx.x & 15;
    if (row >= NN) return;
    const float4* hr = reinterpret_cast<const float4*>(h + (size_t)row * HID);
    float acc = 0.f;
#pragma unroll
    for (int k4 = 0; k4 < HID / 4; ++k4) {
        float4 v = hr[k4];
        acc += v.x * w[(4 * k4 + 0) * HID + c] + v.y * w[(4 * k4 + 1) * HID + c]
             + v.z * w[(4 * k4 + 2) * HID + c] + v.w * w[(4 * k4 + 3) * HID + c];
    }
    out[row * HID + c] = acc * dis[row];
}

__global__ __launch_bounds__(256) void gemm_h_w2(const float* __restrict__ h,
                                                 const float* __restrict__ W,
                                                 const float* __restrict__ dis,
                                                 float* __restrict__ out) {
    int t = blockIdx.x * 256 + threadIdx.x;
    int row = t >> 1;
    int c = t & 1;
    if (row >= NN) return;
    const float* hr = h + (size_t)row * HID;
    float acc = 0.f;
#pragma unroll
    for (int k = 0; k < HID; ++k) acc += hr[k] * W[k * DOUT + c];
    out[row * DOUT + c] = acc * dis[row];
}

// ---------------- aggregation: fused per conv, 196 blocks = 1/CU, natural lockstep ----------------
// All blocks co-resident with identical work (Poisson +-2%) and identical CU
// resources -> they walk slices 0..7 in step without any barrier.

__device__ __forceinline__ void acc_edges(const int* __restrict__ pedge2,
                                          const float4* __restrict__ xs4,
                                          int e0, int e1, int c4, float4& a) {
    int e = e0;
    for (; e + 1 < e1; e += 2) {
        int s0 = pedge2[e];
        int s1 = pedge2[e + 1];
        float4 u = xs4[(s0 << 2) + c4];
        float4 w = xs4[(s1 << 2) + c4];
        a.x += u.x + w.x; a.y += u.y + w.y; a.z += u.z + w.z; a.w += u.w + w.w;
    }
    if (e < e1) {
        float4 u = xs4[(pedge2[e] << 2) + c4];
        a.x += u.x; a.y += u.y; a.z += u.z; a.w += u.w;
    }
}

__device__ __forceinline__ void store_row(float4* buf4, const float* dis, int node,
                                          int c4, const float4& a, const float4& bb,
                                          int relu) {
    if (node < NN) {
        float dd = dis[node];
        float4 v = make_float4(dd * a.x + bb.x, dd * a.y + bb.y,
                               dd * a.z + bb.z, dd * a.w + bb.w);
        if (relu) { v.x = fmaxf(v.x, 0.f); v.y = fmaxf(v.y, 0.f);
                    v.z = fmaxf(v.z, 0.f); v.w = fmaxf(v.w, 0.f); }
        buf4[(node << 2) + c4] = v;
    }
}

__global__ __launch_bounds__(1024, 4) void agg16_all(const int* __restrict__ pedge2,
                                                     const int* __restrict__ rowStart,
                                                     const float* __restrict__ xs,
                                                     const float* __restrict__ dis,
                                                     const float* __restrict__ bias,
                                                     float* __restrict__ buf,
                                                     int relu) {
    int t = threadIdx.x;
    int b = blockIdx.x;
    int base = b << BSH;
    int c4 = t & 3;
    int g = t >> 2;  // rows g, g+256, g+512, g+768 of this bucket
    const float4* xs4 = reinterpret_cast<const float4*>(xs);
    float4* buf4 = reinterpret_cast<float4*>(buf);
    int n0 = base + g, n1 = n0 + 256, n2 = n0 + 512, n3 = n0 + 768;
    float4 a0 = make_float4(0.f, 0.f, 0.f, 0.f);
    float4 a1 = a0, a2 = a0, a3 = a0;
    if (n0 < NN) a0 = xs4[(n0 << 2) + c4];  // self-loop term
    if (n1 < NN) a1 = xs4[(n1 << 2) + c4];
    if (n2 < NN) a2 = xs4[(n2 << 2) + c4];
    if (n3 < NN) a3 = xs4[(n3 << 2) + c4];
    for (int r = 0; r < NCH; ++r) {
        const int* rs = rowStart + (size_t)(b * NCH + r) * BSZ;
        acc_edges(pedge2, xs4, rs[g], rs[g + 1], c4, a0);
        acc_edges(pedge2, xs4, rs[g + 256], rs[g + 257], c4, a1);
        acc_edges(pedge2, xs4, rs[g + 512], rs[g + 513], c4, a2);
        acc_edges(pedge2, xs4, rs[g + 768], rs[g + 769], c4, a3);
    }
    float4 bb = reinterpret_cast<const float4*>(bias)[c4];
    store_row(buf4, dis, n0, c4, a0, bb, relu);
    store_row(buf4, dis, n1, c4, a1, bb, relu);
    store_row(buf4, dis, n2, c4, a2, bb, relu);
    store_row(buf4, dis, n3, c4, a3, bb, relu);
}

// conv2: one thread per dst row, float2 registers, fused bias + log_softmax.
__global__ __launch_bounds__(1024) void agg2_lsm(const int* __restrict__ pedge2,
                                                 const int* __restrict__ rowStart,
                                                 const float* __restrict__ xs,
                                                 const float* __restrict__ dis,
                                                 const float* __restrict__ bias,
                                                 float* __restrict__ out) {
    int t = threadIdx.x;
    int b = blockIdx.x;
    int node = (b << BSH) + t;
    if (node >= NN) return;
    const float2* xs2 = reinterpret_cast<const float2*>(xs);
    float a0 = 0.f, a1 = 0.f;
    for (int s = 0; s < NCH; ++s) {
        const int* rs = rowStart + (size_t)(b * NCH + s) * BSZ;
        int e0 = rs[t], e1 = rs[t + 1];
        for (int e = e0; e < e1; ++e) {
            float2 v = xs2[pedge2[e]];
            a0 += v.x; a1 += v.y;
        }
    }
    float2 sv = xs2[node];
    float d = dis[node];
    float v0 = (a0 + sv.x) * d + bias[0];
    float v1 = (a1 + sv.y) * d + bias[1];
    float m = fmaxf(v0, v1);
    float lse = m + logf(__expf(v0 - m) + __expf(v1 - m));
    reinterpret_cast<float2*>(out)[node] = make_float2(v0 - lse, v1 - lse);
}

// ---------------- launch ----------------

extern "C" void kernel_launch(void* const* d_in, const int* in_sizes, int n_in,
                              void* d_out, int out_size, void* d_ws, size_t ws_size,
                              hipStream_t stream) {
    const float* x = (const float*)d_in[0];
    const int* ei = (const int*)d_in[1];
    const float* W1 = (const float*)d_in[2];
    const float* b1 = (const float*)d_in[3];
    const float* W3 = (const float*)d_in[4];
    const float* b3 = (const float*)d_in[5];
    const float* W2 = (const float*)d_in[6];
    const float* b2 = (const float*)d_in[7];
    float* out = (float*)d_out;

    const int* src = ei;       // edge_index[0]
    const int* dst = ei + NE;  // edge_index[1]

    // workspace layout (~58 MB). bufA aliases pedge (dead after subsort).
    int* W = (int*)d_ws;
    unsigned* pedge = (unsigned*)W;                        // NE
    int* pedge2 = W + NE;                                  // NE
    int* rowStart = W + 2 * (size_t)NE;                    // NK*BSZ + 4
    int* blockHist = rowStart + (size_t)NK * BSZ + 4;      // PB*NK
    int* chunkStart = blockHist + (size_t)PB * NK;         // NK + 4
    float* dis = (float*)(chunkStart + NK + 4);            // NN
    float* bufB = dis + NN;                                // NN*HID
    float* bufA = (float*)W;                               // aliases pedge

    const int B = 256;
    auto cdiv = [](long long a, long long b) { return (int)((a + b - 1) / b); };

    // partition: (bucket,slice) sort -> within-segment dst sort -> CSR + dis
    hist_pass<<<PB, PT, 0, stream>>>(src, dst, blockHist);
    tot_pass<<<cdiv(NK, 256), 256, 0, stream>>>(blockHist, chunkStart);
    scan_keys<<<1, 1024, 0, stream>>>(chunkStart);
    offsets_pass<<<cdiv(NK, 256), 256, 0, stream>>>(blockHist, chunkStart);
    scatter_pass<<<PB, PT, 0, stream>>>(src, dst, blockHist, pedge);
    subsort<<<NB, 1024, 0, stream>>>(pedge, chunkStart, pedge2, rowStart, dis);

    // conv1: bufA = (x@W1)*dis ; fused slice-ordered aggregation into bufB
    gemm_x_w1<<<NN / GXR, B, 0, stream>>>(x, W1, dis, bufA);
    agg16_all<<<NB, 1024, 0, stream>>>(pedge2, rowStart, bufA, dis, b1, bufB, 1);

    // conv3
    gemm_h_w16<<<cdiv(NN, 16), B, 0, stream>>>(bufB, W3, dis, bufA);
    agg16_all<<<NB, 1024, 0, stream>>>(pedge2, rowStart, bufA, dis, b3, bufB, 1);

    // conv2 + log_softmax
    gemm_h_w2<<<cdiv((long long)NN * DOUT, B), B, 0, stream>>>(bufB, W2, dis, bufA);
    agg2_lsm<<<NB, 1024, 0, stream>>>(pedge2, rowStart, bufA, dis, b2, out);
}

// Round 14
// 326.690 us; speedup vs baseline: 2.4129x; 1.2270x over previous
//
#include <hip/hip_runtime.h>

#define NN 200000
#define NE 5000000
#define DIN 128
#define HID 16
#define DOUT 2
#define BSZ 391          // dst-buckets of 391 nodes: 512 buckets exactly
#define NB 512           // 2 blocks/CU on 256 CUs -> full occupancy, exact balance
#define LBITS 9          // local dst index bits (391 < 512)
#define NCH 8            // src slices of 25000 nodes (1.6 MB of xs' @ HID=16)
#define SLICE_DIV 25000
#define NK (NB * NCH)    // 4096 sort keys
#define PB 256           // partition grid blocks
#define PT 512           // partition block threads
#define CAP 2048         // max edges per (bucket,slice) segment; mean 1221, sigma 35

static_assert((size_t)NB * BSZ >= NN, "bucket coverage");
static_assert((NN - 1) / SLICE_DIV == NCH - 1, "slice count");

// ---------------- stage 1: counting sort by (dst/391, src/25000) ----------------

__global__ __launch_bounds__(PT) void hist_pass(const int* __restrict__ src,
                                                const int* __restrict__ dst,
                                                int* __restrict__ blockHist) {
    __shared__ int h[NK];  // 16 KB
    for (int k = threadIdx.x; k < NK; k += PT) h[k] = 0;
    __syncthreads();
    for (int i = blockIdx.x * PT + threadIdx.x; i < NE; i += PB * PT) {
        int dv = dst[i];
        int sv = src[i];
        atomicAdd(&h[((dv / BSZ) << 3) + sv / SLICE_DIV], 1);
    }
    __syncthreads();
    for (int k = threadIdx.x; k < NK; k += PT)
        blockHist[(size_t)blockIdx.x * NK + k] = h[k];
}

// per-key totals -> chunkStart[k] (unscanned)
__global__ __launch_bounds__(256) void tot_pass(const int* __restrict__ blockHist,
                                                int* __restrict__ chunkStart) {
    int k = blockIdx.x * 256 + threadIdx.x;
    if (k >= NK) return;
    int s = 0;
#pragma unroll 8
    for (int b = 0; b < PB; ++b) s += blockHist[(size_t)b * NK + k];
    chunkStart[k] = s;
}

// exclusive scan of chunkStart[0..NK) in place (single block)
__global__ __launch_bounds__(1024) void scan_keys(int* __restrict__ chunkStart) {
    __shared__ int psum[1024];
    int t = threadIdx.x;
    const int KPT = (NK + 1023) / 1024;  // 4
    int k0 = t * KPT; if (k0 > NK) k0 = NK;
    int k1 = k0 + KPT; if (k1 > NK) k1 = NK;
    int vals[KPT];
    int s = 0;
    for (int k = k0; k < k1; ++k) { vals[k - k0] = chunkStart[k]; s += vals[k - k0]; }
    psum[t] = s;
    __syncthreads();
    for (int off = 1; off < 1024; off <<= 1) {
        int add = (t >= off) ? psum[t - off] : 0;
        __syncthreads();
        psum[t] += add;
        __syncthreads();
    }
    int run = psum[t] - s;
    for (int k = k0; k < k1; ++k) { chunkStart[k] = run; run += vals[k - k0]; }
    if (t == 0) chunkStart[NK] = NE;
}

// per-(key, block) exclusive offsets into blockHist
__global__ __launch_bounds__(256) void offsets_pass(int* __restrict__ blockHist,
                                                    const int* __restrict__ chunkStart) {
    int k = blockIdx.x * 256 + threadIdx.x;
    if (k >= NK) return;
    int r = chunkStart[k];
#pragma unroll 8
    for (int b = 0; b < PB; ++b) {
        size_t idx = (size_t)b * NK + k;
        int v = blockHist[idx];
        blockHist[idx] = r;
        r += v;
    }
}

__global__ __launch_bounds__(PT) void scatter_pass(const int* __restrict__ src,
                                                   const int* __restrict__ dst,
                                                   const int* __restrict__ blockHist,
                                                   unsigned* __restrict__ pedge) {
    __shared__ int cur[NK];  // 16 KB
    for (int k = threadIdx.x; k < NK; k += PT)
        cur[k] = blockHist[(size_t)blockIdx.x * NK + k];
    __syncthreads();
    // MUST traverse edges in the same per-block order as hist_pass
    for (int i = blockIdx.x * PT + threadIdx.x; i < NE; i += PB * PT) {
        int sv = src[i];
        int dv = dst[i];
        int bk = dv / BSZ;
        int key = (bk << 3) + sv / SLICE_DIV;
        int pos = atomicAdd(&cur[key], 1);  // LDS atomic only
        pedge[pos] = ((unsigned)sv << LBITS) | (unsigned)(dv - bk * BSZ);
    }
}

// ---------------- stage 2: within-segment sort by dst -> CSR (one-time) ----------------

__global__ __launch_bounds__(512) void subsort(const unsigned* __restrict__ pedge,
                                               const int* __restrict__ chunkStart,
                                               int* __restrict__ pedge2,
                                               int* __restrict__ rowStart,
                                               float* __restrict__ dis) {
    __shared__ unsigned ebuf[CAP];  // 8 KB
    __shared__ int hist[512];
    __shared__ int cur[512];
    __shared__ int wsum[8];
    int t = threadIdx.x;
    int b = blockIdx.x;
    int lane = t & 63, w = t >> 6;  // 8 waves
    int deg = 1;  // self loop
    const unsigned LM = (1u << LBITS) - 1u;
    for (int s = 0; s < NCH; ++s) {
        int seg = b * NCH + s;
        int e0 = chunkStart[seg], e1 = chunkStart[seg + 1];
        int n = e1 - e0;
        hist[t] = 0;
        __syncthreads();
        for (int i = t; i < n; i += 512) {
            unsigned p = pedge[e0 + i];
            ebuf[i] = p;
            atomicAdd(&hist[p & LM], 1);
        }
        __syncthreads();
        int v = hist[t];
        deg += v;
        int inc = v;  // wave-inclusive scan
        for (int off = 1; off < 64; off <<= 1) {
            int nb = __shfl_up(inc, off, 64);
            if (lane >= off) inc += nb;
        }
        if (lane == 63) wsum[w] = inc;
        __syncthreads();
        if (t == 0) {
            int car = 0;
#pragma unroll
            for (int i = 0; i < 8; ++i) { int u = wsum[i]; wsum[i] = car; car += u; }
        }
        __syncthreads();
        int excl = inc - v + wsum[w];
        if (t < BSZ) rowStart[(size_t)seg * BSZ + t] = e0 + excl;
        cur[t] = excl;
        __syncthreads();
        for (int i = t; i < n; i += 512) {
            unsigned p = ebuf[i];
            int pos = atomicAdd(&cur[p & LM], 1);
            pedge2[e0 + pos] = (int)(p >> LBITS);
        }
        __syncthreads();
    }
    int node = b * BSZ + t;
    if (t < BSZ && node < NN) dis[node] = rsqrtf((float)deg);
    if (b == 0 && t == 0) rowStart[(size_t)NK * BSZ] = NE;
}

// ---------------- dense GEMMs, epilogue-scaled by dis[row] (xs' = (h@W)*dis) ----------------

#define GXR 64
#define XPAD 132
__global__ __launch_bounds__(256) void gemm_x_w1(const float* __restrict__ x,
                                                 const float* __restrict__ W,
                                                 const float* __restrict__ dis,
                                                 float* __restrict__ out) {
    __shared__ float w[DIN * HID];     // 8 KB
    __shared__ float xt[GXR * XPAD];   // 33 KB
    int t = threadIdx.x;
    for (int i = t; i < DIN * HID; i += 256) w[i] = W[i];
    int rbase = blockIdx.x * GXR;  // NN = 3125 * 64, no tail
    const float4* xg = reinterpret_cast<const float4*>(x + (size_t)rbase * DIN);
    float4* xt4 = reinterpret_cast<float4*>(xt);
    for (int i = t; i < GXR * (DIN / 4); i += 256) {
        int row = i >> 5, kk = i & 31;
        xt4[row * (XPAD / 4) + kk] = xg[i];
    }
    __syncthreads();
    int row = t >> 2;
    int c0 = (t & 3) * 4;
    const float* xr = xt + row * XPAD;
    float ax = 0.f, ay = 0.f, az = 0.f, aw = 0.f;
#pragma unroll 4
    for (int k = 0; k < DIN; ++k) {
        float xv = xr[k];
        float4 wv = *reinterpret_cast<const float4*>(&w[k * HID + c0]);
        ax += xv * wv.x; ay += xv * wv.y; az += xv * wv.z; aw += xv * wv.w;
    }
    int node = rbase + row;
    float dd = dis[node];
    *reinterpret_cast<float4*>(&out[(size_t)node * HID + c0]) =
        make_float4(ax * dd, ay * dd, az * dd, aw * dd);
}

__global__ __launch_bounds__(256) void gemm_h_w16(const float* __restrict__ h,
                                                  const float* __restrict__ W,
                                                  const float* __restrict__ dis,
                                                  float* __restrict__ out) {
    __shared__ float w[HID * HID];
    if (threadIdx.x < HID * HID) w[threadIdx.x] = W[threadIdx.x];
    __syncthreads();
    int row = blockIdx.x * 16 + (threadIdx.x >> 4);
    int c = threadIdx.x & 15;
    if (row >= NN) return;
    const float4* hr = reinterpret_cast<const float4*>(h + (size_t)row * HID);
    float acc = 0.f;
#pragma unroll
    for (int k4 = 0; k4 < HID / 4; ++k4) {
        float4 v = hr[k4];
        acc += v.x * w[(4 * k4 + 0) * HID + c] + v.y * w[(4 * k4 + 1) * HID + c]
             + v.z * w[(4 * k4 + 2) * HID + c] + v.w * w[(4 * k4 + 3) * HID + c];
    }
    out[row * HID + c] = acc * dis[row];
}

__global__ __launch_bounds__(256) void gemm_h_w2(const float* __restrict__ h,
                                                 const float* __restrict__ W,
                                                 const float* __restrict__ dis,
                                                 float* __restrict__ out) {
    int t = blockIdx.x * 256 + threadIdx.x;
    int row = t >> 1;
    int c = t & 1;
    if (row >= NN) return;
    const float* hr = h + (size_t)row * HID;
    float acc = 0.f;
#pragma unroll
    for (int k = 0; k < HID; ++k) acc += hr[k] * W[k * DOUT + c];
    out[row * DOUT + c] = acc * dis[row];
}

// ---------------- aggregation: fused per conv, 512 blocks = 2/CU, full occupancy ----------------

__device__ __forceinline__ void acc_edges(const int* __restrict__ pedge2,
                                          const float4* __restrict__ xs4,
                                          int e0, int e1, int c4, float4& a) {
    int e = e0;
    for (; e + 1 < e1; e += 2) {
        int s0 = pedge2[e];
        int s1 = pedge2[e + 1];
        float4 u = xs4[(s0 << 2) + c4];
        float4 w = xs4[(s1 << 2) + c4];
        a.x += u.x + w.x; a.y += u.y + w.y; a.z += u.z + w.z; a.w += u.w + w.w;
    }
    if (e < e1) {
        float4 u = xs4[(pedge2[e] << 2) + c4];
        a.x += u.x; a.y += u.y; a.z += u.z; a.w += u.w;
    }
}

__device__ __forceinline__ void store_row(float4* buf4, const float* dis, int node,
                                          int c4, const float4& a, const float4& bb,
                                          int relu) {
    float dd = dis[node];
    float4 v = make_float4(dd * a.x + bb.x, dd * a.y + bb.y,
                           dd * a.z + bb.z, dd * a.w + bb.w);
    if (relu) { v.x = fmaxf(v.x, 0.f); v.y = fmaxf(v.y, 0.f);
                v.z = fmaxf(v.z, 0.f); v.w = fmaxf(v.w, 0.f); }
    buf4[(node << 2) + c4] = v;
}

__global__ __launch_bounds__(1024, 8) void agg16_all(const int* __restrict__ pedge2,
                                                     const int* __restrict__ rowStart,
                                                     const float* __restrict__ xs,
                                                     const float* __restrict__ dis,
                                                     const float* __restrict__ bias,
                                                     float* __restrict__ buf,
                                                     int relu) {
    int t = threadIdx.x;
    int b = blockIdx.x;
    int base = b * BSZ;
    int c4 = t & 3;
    int g = t >> 2;  // rows g and g+256 of this bucket (391 rows)
    const float4* xs4 = reinterpret_cast<const float4*>(xs);
    float4* buf4 = reinterpret_cast<float4*>(buf);
    int d1 = g + 256;
    int n0 = base + g, n1 = base + d1;
    bool r0 = (g < BSZ) && (n0 < NN);
    bool r1 = (d1 < BSZ) && (n1 < NN);
    float4 a0 = make_float4(0.f, 0.f, 0.f, 0.f);
    float4 a1 = a0;
    if (r0) a0 = xs4[(n0 << 2) + c4];  // self-loop term
    if (r1) a1 = xs4[(n1 << 2) + c4];
    for (int r = 0; r < NCH; ++r) {
        const int* rs = rowStart + (size_t)(b * NCH + r) * BSZ;
        if (r0) acc_edges(pedge2, xs4, rs[g], rs[g + 1], c4, a0);
        if (r1) acc_edges(pedge2, xs4, rs[d1], rs[d1 + 1], c4, a1);
    }
    float4 bb = reinterpret_cast<const float4*>(bias)[c4];
    if (r0) store_row(buf4, dis, n0, c4, a0, bb, relu);
    if (r1) store_row(buf4, dis, n1, c4, a1, bb, relu);
}

// conv2: one thread per dst row, float2 registers, fused bias + log_softmax.
__global__ __launch_bounds__(512) void agg2_lsm(const int* __restrict__ pedge2,
                                                const int* __restrict__ rowStart,
                                                const float* __restrict__ xs,
                                                const float* __restrict__ dis,
                                                const float* __restrict__ bias,
                                                float* __restrict__ out) {
    int t = threadIdx.x;
    int b = blockIdx.x;
    if (t >= BSZ) return;
    int node = b * BSZ + t;
    if (node >= NN) return;
    const float2* xs2 = reinterpret_cast<const float2*>(xs);
    float a0 = 0.f, a1 = 0.f;
    for (int s = 0; s < NCH; ++s) {
        const int* rs = rowStart + (size_t)(b * NCH + s) * BSZ;
        int e0 = rs[t], e1 = rs[t + 1];
        for (int e = e0; e < e1; ++e) {
            float2 v = xs2[pedge2[e]];
            a0 += v.x; a1 += v.y;
        }
    }
    float2 sv = xs2[node];
    float d = dis[node];
    float v0 = (a0 + sv.x) * d + bias[0];
    float v1 = (a1 + sv.y) * d + bias[1];
    float m = fmaxf(v0, v1);
    float lse = m + logf(__expf(v0 - m) + __expf(v1 - m));
    reinterpret_cast<float2*>(out)[node] = make_float2(v0 - lse, v1 - lse);
}

// ---------------- launch ----------------

extern "C" void kernel_launch(void* const* d_in, const int* in_sizes, int n_in,
                              void* d_out, int out_size, void* d_ws, size_t ws_size,
                              hipStream_t stream) {
    const float* x = (const float*)d_in[0];
    const int* ei = (const int*)d_in[1];
    const float* W1 = (const float*)d_in[2];
    const float* b1 = (const float*)d_in[3];
    const float* W3 = (const float*)d_in[4];
    const float* b3 = (const float*)d_in[5];
    const float* W2 = (const float*)d_in[6];
    const float* b2 = (const float*)d_in[7];
    float* out = (float*)d_out;

    const int* src = ei;       // edge_index[0]
    const int* dst = ei + NE;  // edge_index[1]

    // workspace layout (~64 MB). bufA aliases pedge (dead after subsort).
    int* W = (int*)d_ws;
    unsigned* pedge = (unsigned*)W;                        // NE
    int* pedge2 = W + NE;                                  // NE
    int* rowStart = W + 2 * (size_t)NE;                    // NK*BSZ + 4
    int* blockHist = rowStart + (size_t)NK * BSZ + 4;      // PB*NK
    int* chunkStart = blockHist + (size_t)PB * NK;         // NK + 4
    float* dis = (float*)(chunkStart + NK + 4);            // NN
    float* bufB = dis + NN;                                // NN*HID
    float* bufA = (float*)W;                               // aliases pedge

    const int B = 256;
    auto cdiv = [](long long a, long long b) { return (int)((a + b - 1) / b); };

    // partition: (bucket,slice) sort -> within-segment dst sort -> CSR + dis
    hist_pass<<<PB, PT, 0, stream>>>(src, dst, blockHist);
    tot_pass<<<cdiv(NK, 256), 256, 0, stream>>>(blockHist, chunkStart);
    scan_keys<<<1, 1024, 0, stream>>>(chunkStart);
    offsets_pass<<<cdiv(NK, 256), 256, 0, stream>>>(blockHist, chunkStart);
    scatter_pass<<<PB, PT, 0, stream>>>(src, dst, blockHist, pedge);
    subsort<<<NB, 512, 0, stream>>>(pedge, chunkStart, pedge2, rowStart, dis);

    // conv1: bufA = (x@W1)*dis ; fused slice-ordered aggregation into bufB
    gemm_x_w1<<<NN / GXR, B, 0, stream>>>(x, W1, dis, bufA);
    agg16_all<<<NB, 1024, 0, stream>>>(pedge2, rowStart, bufA, dis, b1, bufB, 1);

    // conv3
    gemm_h_w16<<<cdiv(NN, 16), B, 0, stream>>>(bufB, W3, dis, bufA);
    agg16_all<<<NB, 1024, 0, stream>>>(pedge2, rowStart, bufA, dis, b3, bufB, 1);

    // conv2 + log_softmax
    gemm_h_w2<<<cdiv((long long)NN * DOUT, B), B, 0, stream>>>(bufB, W2, dis, bufA);
    agg2_lsm<<<NB, 512, 0, stream>>>(pedge2, rowStart, bufA, dis, b2, out);
}